// Round 13
// baseline (203.347 us; speedup 1.0000x reference)
//
#include <hip/hip_runtime.h>
#include <hip/hip_bf16.h>
#include <stdint.h>

#define S_LEN 4096
#define DIM   512
#define NH    8
#define HD    64
#define NZ    8      // KV split factor
#define ZROWS 512    // kv rows per chunk
// 0.125 * log2(e): fold softmax base-2 conversion into the Q projection weights
#define QSCALE 0.18033688011112042f

typedef __attribute__((ext_vector_type(8))) short short8;
typedef __attribute__((ext_vector_type(4))) float f32x4;
typedef __attribute__((ext_vector_type(16))) float f32x16;
typedef __attribute__((ext_vector_type(2))) unsigned uint2v;

__device__ __forceinline__ uint32_t pk2(float lo, float hi) {
  union { __hip_bfloat162 h; uint32_t u; } cv;
  cv.h = __float22bfloat162_rn(float2{lo, hi});
  return cv.u;
}
__device__ __forceinline__ ushort bf1(float x) {
  union { __hip_bfloat16 b; ushort u; } cv;
  cv.b = __float2bfloat16(x);
  return cv.u;
}
__device__ __forceinline__ float bf2f(ushort u) {
  union { uint32_t u; float f; } cv;
  cv.u = (uint32_t)u << 16;
  return cv.f;
}
// raw v_exp_f32: 2^x (args bounded by defer-max, no range fixup needed)
__device__ __forceinline__ float fexp2(float x) {
  float r;
  asm("v_exp_f32 %0, %1" : "=v"(r) : "v"(x));
  return r;
}

// ---------------- prep: x -> bf16 ----------------
__global__ __launch_bounds__(256)
void cast_x(const float* __restrict__ src, ushort* __restrict__ dst) {
  const int i = (blockIdx.x * 256 + threadIdx.x) * 8;
  const float4 a = *reinterpret_cast<const float4*>(src + i);
  const float4 b = *reinterpret_cast<const float4*>(src + i + 4);
  uint4 o;
  o.x = pk2(a.x, a.y); o.y = pk2(a.z, a.w);
  o.z = pk2(b.x, b.y); o.w = pk2(b.z, b.w);
  *reinterpret_cast<uint4*>(dst + i) = o;
}

// ---------------- prep: transpose weights to bf16 ----------------
__global__ __launch_bounds__(256)
void transpose_w(const float* __restrict__ qp, const float* __restrict__ kp,
                 const float* __restrict__ vp, const float* __restrict__ pp,
                 ushort* __restrict__ wbT, ushort* __restrict__ ppT) {
  __shared__ float L[64][65];
  const int z = blockIdx.z;
  const float* src = (z == 0) ? qp : (z == 1) ? kp : (z == 2) ? vp : pp;
  ushort* dst = (z < 3) ? (wbT + (size_t)z * 512 * 512) : ppT;
  const float scale = (z == 0) ? QSCALE : 1.0f;
  const int k0 = blockIdx.x * 64, n0 = blockIdx.y * 64;
  const int r = threadIdx.x >> 2, c0 = (threadIdx.x & 3) * 16;

#pragma unroll
  for (int j = 0; j < 4; ++j) {
    const float4 v =
        *reinterpret_cast<const float4*>(&src[(k0 + r) * 512 + n0 + c0 + 4 * j]);
    L[r][c0 + 4 * j + 0] = v.x * scale;
    L[r][c0 + 4 * j + 1] = v.y * scale;
    L[r][c0 + 4 * j + 2] = v.z * scale;
    L[r][c0 + 4 * j + 3] = v.w * scale;
  }
  __syncthreads();

  uint4 u0, u1;
  u0.x = pk2(L[c0 + 0][r], L[c0 + 1][r]);
  u0.y = pk2(L[c0 + 2][r], L[c0 + 3][r]);
  u0.z = pk2(L[c0 + 4][r], L[c0 + 5][r]);
  u0.w = pk2(L[c0 + 6][r], L[c0 + 7][r]);
  u1.x = pk2(L[c0 + 8][r], L[c0 + 9][r]);
  u1.y = pk2(L[c0 + 10][r], L[c0 + 11][r]);
  u1.z = pk2(L[c0 + 12][r], L[c0 + 13][r]);
  u1.w = pk2(L[c0 + 14][r], L[c0 + 15][r]);
  ushort* d = dst + (size_t)(n0 + r) * 512 + k0 + c0;
  *reinterpret_cast<uint4*>(d) = u0;
  *reinterpret_cast<uint4*>(d + 8) = u1;
}

// ---------------- bf16 MFMA GEMM (BM=128, BN=64, BK=64) ----------------
template <int MODE>
__global__ __launch_bounds__(256)
void gemm_bf16(const ushort* __restrict__ A, const ushort* __restrict__ Bt,
               void* __restrict__ Cout) {
  __shared__ __align__(16) unsigned char lds[24576];  // As 16K | Bs 8K
  const int tid = threadIdx.x;
  const int m0 = blockIdx.x * 128, n0 = blockIdx.y * 64;
  const int lane = tid & 63, w = tid >> 6;
  const int wm = w >> 1, wn = w & 1;
  const int q = lane & 15, g = lane >> 4;
  f32x4 acc[4][2] = {};

  const int ar = tid >> 1, ah = tid & 1;
  const int br = tid >> 2, bq = tid & 3;

  for (int k0 = 0; k0 < 512; k0 += 64) {
    const ushort* ag = A + (size_t)(m0 + ar) * 512 + k0 + ah * 32;
    const uint4 a0 = *reinterpret_cast<const uint4*>(ag);
    const uint4 a1 = *reinterpret_cast<const uint4*>(ag + 8);
    const uint4 a2 = *reinterpret_cast<const uint4*>(ag + 16);
    const uint4 a3 = *reinterpret_cast<const uint4*>(ag + 24);
    const ushort* bg = Bt + (size_t)(n0 + br) * 512 + k0 + bq * 16;
    const uint4 b0 = *reinterpret_cast<const uint4*>(bg);
    const uint4 b1 = *reinterpret_cast<const uint4*>(bg + 8);
    __syncthreads();
    {
      unsigned char* ab = lds + ar * 128;
      const int asw = (ar & 7) << 4;
      *reinterpret_cast<uint4*>(ab + ((ah * 64 + 0) ^ asw)) = a0;
      *reinterpret_cast<uint4*>(ab + ((ah * 64 + 16) ^ asw)) = a1;
      *reinterpret_cast<uint4*>(ab + ((ah * 64 + 32) ^ asw)) = a2;
      *reinterpret_cast<uint4*>(ab + ((ah * 64 + 48) ^ asw)) = a3;
      unsigned char* bb = lds + 16384 + br * 128;
      const int bsw = (br & 7) << 4;
      *reinterpret_cast<uint4*>(bb + ((bq * 32 + 0) ^ bsw)) = b0;
      *reinterpret_cast<uint4*>(bb + ((bq * 32 + 16) ^ bsw)) = b1;
    }
    __syncthreads();

#pragma unroll
    for (int ks = 0; ks < 2; ++ks) {
      short8 bf[2];
#pragma unroll
      for (int ni = 0; ni < 2; ++ni) {
        const int rn = wn * 32 + ni * 16 + q;
        bf[ni] = *reinterpret_cast<const short8*>(
            lds + 16384 + rn * 128 + ((64 * ks + 16 * g) ^ ((rn & 7) << 4)));
      }
#pragma unroll
      for (int mi = 0; mi < 4; ++mi) {
        const int rm = wm * 64 + mi * 16 + q;
        const short8 af = *reinterpret_cast<const short8*>(
            lds + rm * 128 + ((64 * ks + 16 * g) ^ ((rm & 7) << 4)));
#pragma unroll
        for (int ni = 0; ni < 2; ++ni)
          acc[mi][ni] = __builtin_amdgcn_mfma_f32_16x16x32_bf16(
              af, bf[ni], acc[mi][ni], 0, 0, 0);
      }
    }
  }

  if (MODE == 0) {
    ushort* C = (ushort*)Cout;
    const int which = n0 >> 9;
#pragma unroll
    for (int ni = 0; ni < 2; ++ni) {
      const int n = n0 + wn * 32 + ni * 16 + q;
      const int rem = n & 511, hh = rem >> 6, d = rem & 63;
      if (which == 2) {  // V transposed: [64 d][4096 s]
        ushort* base = C + (size_t)(2 * NH + hh) * (size_t)(S_LEN * HD) +
                       (size_t)d * S_LEN;
#pragma unroll
        for (int mi = 0; mi < 4; ++mi) {
          const int s = m0 + wm * 64 + mi * 16 + 4 * g;
          uint2 pw;
          pw.x = pk2(acc[mi][ni][0], acc[mi][ni][1]);
          pw.y = pk2(acc[mi][ni][2], acc[mi][ni][3]);
          *reinterpret_cast<uint2*>(base + s) = pw;
        }
      } else {
        ushort* base =
            C + ((size_t)which * NH + hh) * (size_t)(S_LEN * HD) + d;
#pragma unroll
        for (int mi = 0; mi < 4; ++mi) {
          const int s = m0 + wm * 64 + mi * 16 + 4 * g;
#pragma unroll
          for (int r = 0; r < 4; ++r)
            base[(size_t)(s + r) * HD] = bf1(acc[mi][ni][r]);
        }
      }
    }
  } else {
    float* C = (float*)Cout;
#pragma unroll
    for (int ni = 0; ni < 2; ++ni) {
      const int n = n0 + wn * 32 + ni * 16 + q;
#pragma unroll
      for (int mi = 0; mi < 4; ++mi) {
        const int s = m0 + wm * 64 + mi * 16 + 4 * g;
#pragma unroll
        for (int r = 0; r < 4; ++r)
          C[(size_t)(s + r) * 512 + n] = acc[mi][ni][r];
      }
    }
  }
}

// ------- MFMA flash attention: defer-max, 2 Q-blocks/wave, KV-split-8 -------
// R11's proven kernel with split 4->8: block = 4 waves, 256 q rows, 8 kv tiles
// (512 rows). Grid = 64 combos x 16 qb = 1024 blocks = 4 blocks/CU -> 4
// waves/SIMD of independent chains (launch_bounds(256,4)).
// Linear block id % 8 == h -> each XCD's L2 caches one head's K/V.
__global__ __launch_bounds__(256, 4)
void attn_mfma32(const ushort* __restrict__ QKV, ushort* __restrict__ Opart,
                 float2* __restrict__ ML) {
  __shared__ __align__(16) unsigned char lds[32768];  // 2 buf x (K 8K | Vt 8K)
  const int tid = threadIdx.x;
  const int combo = blockIdx.x;
  const int h = combo & 7, z = combo >> 3;
  const int qb = blockIdx.y;
  const int lane = tid & 63, w = tid >> 6;
  const int r31 = lane & 31, hh = lane >> 5;

  const size_t plane = (size_t)S_LEN * HD;
  const ushort* Qp = QKV + (size_t)h * plane;
  const ushort* Kp = QKV + (size_t)(NH + h) * plane;       // [4096][64]
  const ushort* Vp = QKV + (size_t)(2 * NH + h) * plane;   // [64][4096]

  const int qbase = qb * 256 + w * 64;
  const int qrowA = qbase + r31, qrowB = qbase + 32 + r31;

  // Q fragments for both q-blocks: qf[ks] = Q[qrow][16ks + 8hh .. +7]
  short8 qfA[4], qfB[4];
  {
    const ushort* qa = Qp + (size_t)qrowA * HD + 8 * hh;
    const ushort* qbp = Qp + (size_t)qrowB * HD + 8 * hh;
#pragma unroll
    for (int ks = 0; ks < 4; ++ks) {
      qfA[ks] = *reinterpret_cast<const short8*>(qa + 16 * ks);
      qfB[ks] = *reinterpret_cast<const short8*>(qbp + 16 * ks);
    }
  }

  // swizzled fragment-read column offsets (shared by K and Vt, rows 128B)
  int roff[4];
#pragma unroll
  for (int ks = 0; ks < 4; ++ks)
    roff[ks] = (((2 * ks + hh) << 4) ^ ((r31 & 7) << 4));
  const int rbase = r31 * 128;

  // staging: thread -> (row 0..63, 32B segment 0..3) for both K and Vt
  const int trow = tid >> 2, seg = tid & 3;
  const int tsw = (trow & 7) << 4;
  const int wk0 = trow * 128 + ((seg * 32) ^ tsw);
  const int wk1 = trow * 128 + ((seg * 32 + 16) ^ tsw);
  const ushort* kgbase = Kp + (size_t)(z * ZROWS + trow) * HD + seg * 16;
  const ushort* vgbase = Vp + (size_t)trow * S_LEN + z * ZROWS + seg * 16;

  f32x16 oA[2] = {}, oB[2] = {};
  float mA = -1e30f, lA = 0.f, mB = -1e30f, lB = 0.f;

  uint4 kst0 = *reinterpret_cast<const uint4*>(kgbase);
  uint4 kst1 = *reinterpret_cast<const uint4*>(kgbase + 8);
  uint4 vst0 = *reinterpret_cast<const uint4*>(vgbase);
  uint4 vst1 = *reinterpret_cast<const uint4*>(vgbase + 8);

  for (int t = 0; t < 8; ++t) {
    const int po = (t & 1) << 14;  // buffer select (0 / 16384)
    *reinterpret_cast<uint4*>(lds + (wk0 | po)) = kst0;
    *reinterpret_cast<uint4*>(lds + (wk1 | po)) = kst1;
    *reinterpret_cast<uint4*>(lds + ((8192 + wk0) | po)) = vst0;
    *reinterpret_cast<uint4*>(lds + ((8192 + wk1) | po)) = vst1;
    __syncthreads();

    // issue next tile's loads (wraps on last iter; data unused)
    const int tn = (t + 1) & 7;
    kst0 = *reinterpret_cast<const uint4*>(kgbase + tn * 4096);
    kst1 = *reinterpret_cast<const uint4*>(kgbase + tn * 4096 + 8);
    vst0 = *reinterpret_cast<const uint4*>(vgbase + tn * 64);
    vst1 = *reinterpret_cast<const uint4*>(vgbase + tn * 64 + 8);

#pragma unroll
    for (int c = 0; c < 2; ++c) {
      // ---- S^T = K * Q^T for 32-kpos chunk c, both q-blocks ----
      f32x16 sA = {}, sB = {};
      __builtin_amdgcn_s_setprio(1);
#pragma unroll
      for (int ks = 0; ks < 4; ++ks) {
        const short8 af = *reinterpret_cast<const short8*>(
            lds + ((c * 4096 + rbase + roff[ks]) | po));
        sA = __builtin_amdgcn_mfma_f32_32x32x16_bf16(af, qfA[ks], sA, 0, 0, 0);
        sB = __builtin_amdgcn_mfma_f32_32x32x16_bf16(af, qfB[ks], sB, 0, 0, 0);
      }
      __builtin_amdgcn_s_setprio(0);

      // ---- defer-max online softmax (THR=8), per q-block ----
      {
        float mv[8];
#pragma unroll
        for (int i = 0; i < 8; ++i) mv[i] = fmaxf(sA[i], sA[i + 8]);
#pragma unroll
        for (int i = 0; i < 4; ++i) mv[i] = fmaxf(mv[i], mv[i + 4]);
        float mx = fmaxf(fmaxf(mv[0], mv[1]), fmaxf(mv[2], mv[3]));
        mx = fmaxf(mx, __shfl_xor(mx, 32));
        const bool grow = mx > mA + 8.0f;
        if (__any(grow)) {
          const float mn = grow ? mx : mA;
          const float alpha = grow ? fexp2(mA - mn) : 1.0f;
          lA *= alpha;
#pragma unroll
          for (int i = 0; i < 16; ++i) { oA[0][i] *= alpha; oA[1][i] *= alpha; }
          mA = mn;
        }
        float r0 = 0.f, r1 = 0.f, r2 = 0.f, r3 = 0.f;
#pragma unroll
        for (int i = 0; i < 16; i += 4) {
          sA[i + 0] = fexp2(sA[i + 0] - mA); r0 += sA[i + 0];
          sA[i + 1] = fexp2(sA[i + 1] - mA); r1 += sA[i + 1];
          sA[i + 2] = fexp2(sA[i + 2] - mA); r2 += sA[i + 2];
          sA[i + 3] = fexp2(sA[i + 3] - mA); r3 += sA[i + 3];
        }
        lA += (r0 + r1) + (r2 + r3);
      }
      {
        float mv[8];
#pragma unroll
        for (int i = 0; i < 8; ++i) mv[i] = fmaxf(sB[i], sB[i + 8]);
#pragma unroll
        for (int i = 0; i < 4; ++i) mv[i] = fmaxf(mv[i], mv[i + 4]);
        float mx = fmaxf(fmaxf(mv[0], mv[1]), fmaxf(mv[2], mv[3]));
        mx = fmaxf(mx, __shfl_xor(mx, 32));
        const bool grow = mx > mB + 8.0f;
        if (__any(grow)) {
          const float mn = grow ? mx : mB;
          const float alpha = grow ? fexp2(mB - mn) : 1.0f;
          lB *= alpha;
#pragma unroll
          for (int i = 0; i < 16; ++i) { oB[0][i] *= alpha; oB[1][i] *= alpha; }
          mB = mn;
        }
        float r0 = 0.f, r1 = 0.f, r2 = 0.f, r3 = 0.f;
#pragma unroll
        for (int i = 0; i < 16; i += 4) {
          sB[i + 0] = fexp2(sB[i + 0] - mB); r0 += sB[i + 0];
          sB[i + 1] = fexp2(sB[i + 1] - mB); r1 += sB[i + 1];
          sB[i + 2] = fexp2(sB[i + 2] - mB); r2 += sB[i + 2];
          sB[i + 3] = fexp2(sB[i + 3] - mB); r3 += sB[i + 3];
        }
        lB += (r0 + r1) + (r2 + r3);
      }

      // ---- P -> bf16, redistribute across lane halves (in-register) ----
      short8 pfA[2], pfB[2];
#pragma unroll
      for (int e = 0; e < 2; ++e) {
        const int bb = 2 * e;
        {
          const uint32_t u00 = pk2(sA[4 * bb + 0], sA[4 * bb + 1]);
          const uint32_t u01 = pk2(sA[4 * bb + 2], sA[4 * bb + 3]);
          const uint32_t u10 = pk2(sA[4 * bb + 4], sA[4 * bb + 5]);
          const uint32_t u11 = pk2(sA[4 * bb + 6], sA[4 * bb + 7]);
          const uint2v se0 =
              __builtin_amdgcn_permlane32_swap(u00, u10, false, false);
          const uint2v se1 =
              __builtin_amdgcn_permlane32_swap(u01, u11, false, false);
          uint32_t fr[4] = {se0.x, se1.x, se0.y, se1.y};
          pfA[e] = *reinterpret_cast<short8*>(fr);
        }
        {
          const uint32_t u00 = pk2(sB[4 * bb + 0], sB[4 * bb + 1]);
          const uint32_t u01 = pk2(sB[4 * bb + 2], sB[4 * bb + 3]);
          const uint32_t u10 = pk2(sB[4 * bb + 4], sB[4 * bb + 5]);
          const uint32_t u11 = pk2(sB[4 * bb + 6], sB[4 * bb + 7]);
          const uint2v se0 =
              __builtin_amdgcn_permlane32_swap(u00, u10, false, false);
          const uint2v se1 =
              __builtin_amdgcn_permlane32_swap(u01, u11, false, false);
          uint32_t fr[4] = {se0.x, se1.x, se0.y, se1.y};
          pfB[e] = *reinterpret_cast<short8*>(fr);
        }
      }

      // ---- O^T += V^T * P^T (each vf read feeds both q-blocks) ----
      __builtin_amdgcn_s_setprio(1);
#pragma unroll
      for (int dt = 0; dt < 2; ++dt)
#pragma unroll
        for (int e = 0; e < 2; ++e) {
          const int kg = 2 * c + e;
          const short8 vf = *reinterpret_cast<const short8*>(
              lds + ((8192 + (32 * dt + r31) * 128 +
                      (((32 * kg + 16 * hh)) ^ ((r31 & 7) << 4))) |
                     po));
          oA[dt] = __builtin_amdgcn_mfma_f32_32x32x16_bf16(vf, pfA[e], oA[dt],
                                                           0, 0, 0);
          oB[dt] = __builtin_amdgcn_mfma_f32_32x32x16_bf16(vf, pfB[e], oB[dt],
                                                           0, 0, 0);
        }
      __builtin_amdgcn_s_setprio(0);
    }
  }

  // ---- cross-half reduce of l (lane l / l+32 hold different kpos halves) ----
  lA += __shfl_xor(lA, 32);
  lB += __shfl_xor(lB, 32);

  // ---- store partials ----
  if (lane < 32) {
    ML[(size_t)combo * S_LEN + qrowA] = float2{mA, lA};
    ML[(size_t)combo * S_LEN + qrowB] = float2{mB, lB};
  }
  ushort* obA = Opart + ((size_t)combo * S_LEN + qrowA) * HD;
  ushort* obB = Opart + ((size_t)combo * S_LEN + qrowB) * HD;
#pragma unroll
  for (int dt = 0; dt < 2; ++dt)
#pragma unroll
    for (int rq = 0; rq < 4; ++rq) {
      const int d = 32 * dt + 8 * rq + 4 * hh;
      uint2 pwA, pwB;
      pwA.x = pk2(oA[dt][4 * rq + 0], oA[dt][4 * rq + 1]);
      pwA.y = pk2(oA[dt][4 * rq + 2], oA[dt][4 * rq + 3]);
      pwB.x = pk2(oB[dt][4 * rq + 0], oB[dt][4 * rq + 1]);
      pwB.y = pk2(oB[dt][4 * rq + 2], oB[dt][4 * rq + 3]);
      *reinterpret_cast<uint2*>(obA + d) = pwA;
      *reinterpret_cast<uint2*>(obB + d) = pwB;
    }
}

// ---------------- combine the 8 kv-chunk partials (m/l merge) ----------------
__global__ __launch_bounds__(256)
void combine(const ushort* __restrict__ Opart, const float2* __restrict__ ML,
             ushort* __restrict__ ob) {
  const int t = threadIdx.x;
  const int qq = t & 63, ds = t >> 6;
  const int q = blockIdx.x * 64 + qq;
  const int h = blockIdx.y;

  float m = -1e30f, mz[NZ], lz[NZ];
#pragma unroll
  for (int z = 0; z < NZ; ++z) {
    const float2 v = ML[(size_t)(z * 8 + h) * S_LEN + q];
    mz[z] = v.x; lz[z] = v.y;
    m = fmaxf(m, v.x);
  }
  float wz[NZ], l = 0.f;
#pragma unroll
  for (int z = 0; z < NZ; ++z) {
    wz[z] = fexp2(mz[z] - m);
    l += wz[z] * lz[z];
  }
  const float inv = 1.0f / l;
#pragma unroll
  for (int z = 0; z < NZ; ++z) wz[z] *= inv;

  float acc[16];
#pragma unroll
  for (int i = 0; i < 16; ++i) acc[i] = 0.f;
#pragma unroll
  for (int z = 0; z < NZ; ++z) {
    const ushort* src =
        Opart + (((size_t)(z * 8 + h) * S_LEN) + q) * HD + ds * 16;
    const uint4 u0 = *reinterpret_cast<const uint4*>(src);
    const uint4 u1 = *reinterpret_cast<const uint4*>(src + 8);
    const ushort* e0 = reinterpret_cast<const ushort*>(&u0);
    const ushort* e1 = reinterpret_cast<const ushort*>(&u1);
#pragma unroll
    for (int i = 0; i < 8; ++i) {
      acc[i] = fmaf(wz[z], bf2f(e0[i]), acc[i]);
      acc[i + 8] = fmaf(wz[z], bf2f(e1[i]), acc[i + 8]);
    }
  }
  uint32_t pk[8];
#pragma unroll
  for (int i = 0; i < 8; ++i)
    pk[i] = pk2(acc[2 * i], acc[2 * i + 1]);
  ushort* dst = ob + (size_t)q * DIM + h * 64 + ds * 16;
  *reinterpret_cast<uint4*>(dst) = *reinterpret_cast<uint4*>(pk);
  *reinterpret_cast<uint4*>(dst + 8) = *reinterpret_cast<uint4*>(pk + 4);
}

extern "C" void kernel_launch(void* const* d_in, const int* in_sizes, int n_in,
                              void* d_out, int out_size, void* d_ws, size_t ws_size,
                              hipStream_t stream) {
  const float* x  = (const float*)d_in[0];
  const float* qp = (const float*)d_in[1];
  const float* kp = (const float*)d_in[2];
  const float* vp = (const float*)d_in[3];
  const float* pp = (const float*)d_in[4];
  float* out = (float*)d_out;

  unsigned char* ws = (unsigned char*)d_ws;
  ushort* xb    = (ushort*)(ws);                       // 4 MB
  ushort* qkvb  = (ushort*)(ws + ((size_t)4 << 20));   // 12 MB [3][8] planes
  ushort* ob    = (ushort*)(ws + ((size_t)16 << 20));  // 4 MB [4096][512]
  ushort* wbT   = (ushort*)(ws + ((size_t)20 << 20));  // 1.5 MB
  ushort* ppT   = (ushort*)(ws + ((size_t)22 << 20));  // 0.5 MB
  ushort* opart = (ushort*)(ws + ((size_t)23 << 20));  // 32 MB [64][4096][64]
  float2* ml    = (float2*)(ws + ((size_t)55 << 20));  // 2 MB [64][4096]

  cast_x<<<dim3(1024), dim3(256), 0, stream>>>(x, xb);
  transpose_w<<<dim3(8, 8, 4), dim3(256), 0, stream>>>(qp, kp, vp, pp, wbT, ppT);
  gemm_bf16<0><<<dim3(32, 24), dim3(256), 0, stream>>>(xb, wbT, qkvb);
  attn_mfma32<<<dim3(64, 16), dim3(256), 0, stream>>>(qkvb, opart, ml);
  combine<<<dim3(64, 8), dim3(256), 0, stream>>>(opart, ml, ob);
  gemm_bf16<1><<<dim3(32, 8), dim3(256), 0, stream>>>(ob, ppT, out);
}

// Round 14
// 94.286 us; speedup vs baseline: 2.1567x; 2.1567x over previous
//
#include <hip/hip_runtime.h>
#include <hip/hip_bf16.h>
#include <stdint.h>

#define S_LEN 4096
#define DIM   512
#define NH    8
#define HD    64
#define NZ    4      // KV split factor
#define ZROWS 1024   // kv rows per chunk
// 0.125 * log2(e): fold softmax base-2 conversion into the Q projection weights
#define QSCALE 0.18033688011112042f

typedef __attribute__((ext_vector_type(8))) short short8;
typedef __attribute__((ext_vector_type(4))) float f32x4;
typedef __attribute__((ext_vector_type(16))) float f32x16;
typedef __attribute__((ext_vector_type(2))) unsigned uint2v;

__device__ __forceinline__ uint32_t pk2(float lo, float hi) {
  union { __hip_bfloat162 h; uint32_t u; } cv;
  cv.h = __float22bfloat162_rn(float2{lo, hi});
  return cv.u;
}
__device__ __forceinline__ ushort bf1(float x) {
  union { __hip_bfloat16 b; ushort u; } cv;
  cv.b = __float2bfloat16(x);
  return cv.u;
}
__device__ __forceinline__ float bf2f(ushort u) {
  union { uint32_t u; float f; } cv;
  cv.u = (uint32_t)u << 16;
  return cv.f;
}
// raw v_exp_f32: 2^x (args bounded by defer-max, no range fixup needed)
__device__ __forceinline__ float fexp2(float x) {
  float r;
  asm("v_exp_f32 %0, %1" : "=v"(r) : "v"(x));
  return r;
}

// ---------------- prep: x -> bf16 ----------------
__global__ __launch_bounds__(256)
void cast_x(const float* __restrict__ src, ushort* __restrict__ dst) {
  const int i = (blockIdx.x * 256 + threadIdx.x) * 8;
  const float4 a = *reinterpret_cast<const float4*>(src + i);
  const float4 b = *reinterpret_cast<const float4*>(src + i + 4);
  uint4 o;
  o.x = pk2(a.x, a.y); o.y = pk2(a.z, a.w);
  o.z = pk2(b.x, b.y); o.w = pk2(b.z, b.w);
  *reinterpret_cast<uint4*>(dst + i) = o;
}

// ---------------- prep: transpose weights to bf16 ----------------
__global__ __launch_bounds__(256)
void transpose_w(const float* __restrict__ qp, const float* __restrict__ kp,
                 const float* __restrict__ vp, const float* __restrict__ pp,
                 ushort* __restrict__ wbT, ushort* __restrict__ ppT) {
  __shared__ float L[64][65];
  const int z = blockIdx.z;
  const float* src = (z == 0) ? qp : (z == 1) ? kp : (z == 2) ? vp : pp;
  ushort* dst = (z < 3) ? (wbT + (size_t)z * 512 * 512) : ppT;
  const float scale = (z == 0) ? QSCALE : 1.0f;
  const int k0 = blockIdx.x * 64, n0 = blockIdx.y * 64;
  const int r = threadIdx.x >> 2, c0 = (threadIdx.x & 3) * 16;

#pragma unroll
  for (int j = 0; j < 4; ++j) {
    const float4 v =
        *reinterpret_cast<const float4*>(&src[(k0 + r) * 512 + n0 + c0 + 4 * j]);
    L[r][c0 + 4 * j + 0] = v.x * scale;
    L[r][c0 + 4 * j + 1] = v.y * scale;
    L[r][c0 + 4 * j + 2] = v.z * scale;
    L[r][c0 + 4 * j + 3] = v.w * scale;
  }
  __syncthreads();

  uint4 u0, u1;
  u0.x = pk2(L[c0 + 0][r], L[c0 + 1][r]);
  u0.y = pk2(L[c0 + 2][r], L[c0 + 3][r]);
  u0.z = pk2(L[c0 + 4][r], L[c0 + 5][r]);
  u0.w = pk2(L[c0 + 6][r], L[c0 + 7][r]);
  u1.x = pk2(L[c0 + 8][r], L[c0 + 9][r]);
  u1.y = pk2(L[c0 + 10][r], L[c0 + 11][r]);
  u1.z = pk2(L[c0 + 12][r], L[c0 + 13][r]);
  u1.w = pk2(L[c0 + 14][r], L[c0 + 15][r]);
  ushort* d = dst + (size_t)(n0 + r) * 512 + k0 + c0;
  *reinterpret_cast<uint4*>(d) = u0;
  *reinterpret_cast<uint4*>(d + 8) = u1;
}

// ---------------- bf16 MFMA GEMM (BM=128, BN=64, BK=64) ----------------
template <int MODE>
__global__ __launch_bounds__(256)
void gemm_bf16(const ushort* __restrict__ A, const ushort* __restrict__ Bt,
               void* __restrict__ Cout) {
  __shared__ __align__(16) unsigned char lds[24576];  // As 16K | Bs 8K
  const int tid = threadIdx.x;
  const int m0 = blockIdx.x * 128, n0 = blockIdx.y * 64;
  const int lane = tid & 63, w = tid >> 6;
  const int wm = w >> 1, wn = w & 1;
  const int q = lane & 15, g = lane >> 4;
  f32x4 acc[4][2] = {};

  const int ar = tid >> 1, ah = tid & 1;
  const int br = tid >> 2, bq = tid & 3;

  for (int k0 = 0; k0 < 512; k0 += 64) {
    const ushort* ag = A + (size_t)(m0 + ar) * 512 + k0 + ah * 32;
    const uint4 a0 = *reinterpret_cast<const uint4*>(ag);
    const uint4 a1 = *reinterpret_cast<const uint4*>(ag + 8);
    const uint4 a2 = *reinterpret_cast<const uint4*>(ag + 16);
    const uint4 a3 = *reinterpret_cast<const uint4*>(ag + 24);
    const ushort* bg = Bt + (size_t)(n0 + br) * 512 + k0 + bq * 16;
    const uint4 b0 = *reinterpret_cast<const uint4*>(bg);
    const uint4 b1 = *reinterpret_cast<const uint4*>(bg + 8);
    __syncthreads();
    {
      unsigned char* ab = lds + ar * 128;
      const int asw = (ar & 7) << 4;
      *reinterpret_cast<uint4*>(ab + ((ah * 64 + 0) ^ asw)) = a0;
      *reinterpret_cast<uint4*>(ab + ((ah * 64 + 16) ^ asw)) = a1;
      *reinterpret_cast<uint4*>(ab + ((ah * 64 + 32) ^ asw)) = a2;
      *reinterpret_cast<uint4*>(ab + ((ah * 64 + 48) ^ asw)) = a3;
      unsigned char* bb = lds + 16384 + br * 128;
      const int bsw = (br & 7) << 4;
      *reinterpret_cast<uint4*>(bb + ((bq * 32 + 0) ^ bsw)) = b0;
      *reinterpret_cast<uint4*>(bb + ((bq * 32 + 16) ^ bsw)) = b1;
    }
    __syncthreads();

#pragma unroll
    for (int ks = 0; ks < 2; ++ks) {
      short8 bf[2];
#pragma unroll
      for (int ni = 0; ni < 2; ++ni) {
        const int rn = wn * 32 + ni * 16 + q;
        bf[ni] = *reinterpret_cast<const short8*>(
            lds + 16384 + rn * 128 + ((64 * ks + 16 * g) ^ ((rn & 7) << 4)));
      }
#pragma unroll
      for (int mi = 0; mi < 4; ++mi) {
        const int rm = wm * 64 + mi * 16 + q;
        const short8 af = *reinterpret_cast<const short8*>(
            lds + rm * 128 + ((64 * ks + 16 * g) ^ ((rm & 7) << 4)));
#pragma unroll
        for (int ni = 0; ni < 2; ++ni)
          acc[mi][ni] = __builtin_amdgcn_mfma_f32_16x16x32_bf16(
              af, bf[ni], acc[mi][ni], 0, 0, 0);
      }
    }
  }

  if (MODE == 0) {
    ushort* C = (ushort*)Cout;
    const int which = n0 >> 9;
#pragma unroll
    for (int ni = 0; ni < 2; ++ni) {
      const int n = n0 + wn * 32 + ni * 16 + q;
      const int rem = n & 511, hh = rem >> 6, d = rem & 63;
      if (which == 2) {  // V transposed: [64 d][4096 s]
        ushort* base = C + (size_t)(2 * NH + hh) * (size_t)(S_LEN * HD) +
                       (size_t)d * S_LEN;
#pragma unroll
        for (int mi = 0; mi < 4; ++mi) {
          const int s = m0 + wm * 64 + mi * 16 + 4 * g;
          uint2 pw;
          pw.x = pk2(acc[mi][ni][0], acc[mi][ni][1]);
          pw.y = pk2(acc[mi][ni][2], acc[mi][ni][3]);
          *reinterpret_cast<uint2*>(base + s) = pw;
        }
      } else {
        ushort* base =
            C + ((size_t)which * NH + hh) * (size_t)(S_LEN * HD) + d;
#pragma unroll
        for (int mi = 0; mi < 4; ++mi) {
          const int s = m0 + wm * 64 + mi * 16 + 4 * g;
#pragma unroll
          for (int r = 0; r < 4; ++r)
            base[(size_t)(s + r) * HD] = bf1(acc[mi][ni][r]);
        }
      }
    }
  } else {
    float* C = (float*)Cout;
#pragma unroll
    for (int ni = 0; ni < 2; ++ni) {
      const int n = n0 + wn * 32 + ni * 16 + q;
#pragma unroll
      for (int mi = 0; mi < 4; ++mi) {
        const int s = m0 + wm * 64 + mi * 16 + 4 * g;
#pragma unroll
        for (int r = 0; r < 4; ++r)
          C[(size_t)(s + r) * 512 + n] = acc[mi][ni][r];
      }
    }
  }
}

// ------- MFMA flash attention: MERGED defer-max softmax, 2 Q-blocks/wave -------
// R11 base (split 4, LB(256,2), 16 tiles) with R8's merged softmax: per tile,
// QK for BOTH 32-kpos chunks first (16 clustered MFMAs), then ONE softmax
// section (4 independent exp chains: sA0/sA1/sB0/sB1), then pack, then 16
// clustered PV MFMAs. Halves serial softmax sections per tile vs R11.
__global__ __launch_bounds__(256, 2)
void attn_mfma32(const ushort* __restrict__ QKV, ushort* __restrict__ Opart,
                 float2* __restrict__ ML) {
  __shared__ __align__(16) unsigned char lds[32768];  // 2 buf x (K 8K | Vt 8K)
  const int tid = threadIdx.x;
  const int combo = blockIdx.x;
  const int h = combo & 7, z = combo >> 3;
  const int qb = blockIdx.y;
  const int lane = tid & 63, w = tid >> 6;
  const int r31 = lane & 31, hh = lane >> 5;

  const size_t plane = (size_t)S_LEN * HD;
  const ushort* Qp = QKV + (size_t)h * plane;
  const ushort* Kp = QKV + (size_t)(NH + h) * plane;       // [4096][64]
  const ushort* Vp = QKV + (size_t)(2 * NH + h) * plane;   // [64][4096]

  const int qbase = qb * 256 + w * 64;
  const int qrowA = qbase + r31, qrowB = qbase + 32 + r31;

  // Q fragments for both q-blocks: qf[ks] = Q[qrow][16ks + 8hh .. +7]
  short8 qfA[4], qfB[4];
  {
    const ushort* qa = Qp + (size_t)qrowA * HD + 8 * hh;
    const ushort* qbp = Qp + (size_t)qrowB * HD + 8 * hh;
#pragma unroll
    for (int ks = 0; ks < 4; ++ks) {
      qfA[ks] = *reinterpret_cast<const short8*>(qa + 16 * ks);
      qfB[ks] = *reinterpret_cast<const short8*>(qbp + 16 * ks);
    }
  }

  // swizzled fragment-read column offsets (shared by K and Vt, rows 128B)
  int roff[4];
#pragma unroll
  for (int ks = 0; ks < 4; ++ks)
    roff[ks] = (((2 * ks + hh) << 4) ^ ((r31 & 7) << 4));
  const int rbase = r31 * 128;

  // staging: thread -> (row 0..63, 32B segment 0..3) for both K and Vt
  const int trow = tid >> 2, seg = tid & 3;
  const int tsw = (trow & 7) << 4;
  const int wk0 = trow * 128 + ((seg * 32) ^ tsw);
  const int wk1 = trow * 128 + ((seg * 32 + 16) ^ tsw);
  const ushort* kgbase = Kp + (size_t)(z * ZROWS + trow) * HD + seg * 16;
  const ushort* vgbase = Vp + (size_t)trow * S_LEN + z * ZROWS + seg * 16;

  f32x16 oA[2] = {}, oB[2] = {};
  float mA = -1e30f, lA = 0.f, mB = -1e30f, lB = 0.f;

  uint4 kst0 = *reinterpret_cast<const uint4*>(kgbase);
  uint4 kst1 = *reinterpret_cast<const uint4*>(kgbase + 8);
  uint4 vst0 = *reinterpret_cast<const uint4*>(vgbase);
  uint4 vst1 = *reinterpret_cast<const uint4*>(vgbase + 8);

  for (int t = 0; t < 16; ++t) {
    const int po = (t & 1) << 14;  // buffer select (0 / 16384)
    *reinterpret_cast<uint4*>(lds + (wk0 | po)) = kst0;
    *reinterpret_cast<uint4*>(lds + (wk1 | po)) = kst1;
    *reinterpret_cast<uint4*>(lds + ((8192 + wk0) | po)) = vst0;
    *reinterpret_cast<uint4*>(lds + ((8192 + wk1) | po)) = vst1;
    __syncthreads();

    // issue next tile's loads (wraps on last iter; data unused)
    const int tn = (t + 1) & 15;
    kst0 = *reinterpret_cast<const uint4*>(kgbase + tn * 4096);
    kst1 = *reinterpret_cast<const uint4*>(kgbase + tn * 4096 + 8);
    vst0 = *reinterpret_cast<const uint4*>(vgbase + tn * 64);
    vst1 = *reinterpret_cast<const uint4*>(vgbase + tn * 64 + 8);

    // ---- S^T = K * Q^T, BOTH 32-kpos chunks, both q-blocks (16 MFMA) ----
    f32x16 sA0 = {}, sA1 = {}, sB0 = {}, sB1 = {};
    __builtin_amdgcn_s_setprio(1);
#pragma unroll
    for (int ks = 0; ks < 4; ++ks) {
      const short8 af0 = *reinterpret_cast<const short8*>(
          lds + ((rbase + roff[ks]) | po));
      const short8 af1 = *reinterpret_cast<const short8*>(
          lds + ((4096 + rbase + roff[ks]) | po));
      sA0 = __builtin_amdgcn_mfma_f32_32x32x16_bf16(af0, qfA[ks], sA0, 0, 0, 0);
      sB0 = __builtin_amdgcn_mfma_f32_32x32x16_bf16(af0, qfB[ks], sB0, 0, 0, 0);
      sA1 = __builtin_amdgcn_mfma_f32_32x32x16_bf16(af1, qfA[ks], sA1, 0, 0, 0);
      sB1 = __builtin_amdgcn_mfma_f32_32x32x16_bf16(af1, qfB[ks], sB1, 0, 0, 0);
    }
    __builtin_amdgcn_s_setprio(0);

    // ---- ONE merged defer-max softmax section (THR=8), per q-block ----
    {
      float mv[8];
#pragma unroll
      for (int i = 0; i < 8; ++i)
        mv[i] = fmaxf(fmaxf(sA0[i], sA0[i + 8]), fmaxf(sA1[i], sA1[i + 8]));
#pragma unroll
      for (int i = 0; i < 4; ++i) mv[i] = fmaxf(mv[i], mv[i + 4]);
      float mx = fmaxf(fmaxf(mv[0], mv[1]), fmaxf(mv[2], mv[3]));
      mx = fmaxf(mx, __shfl_xor(mx, 32));
      const bool grow = mx > mA + 8.0f;
      if (__any(grow)) {
        const float mn = grow ? mx : mA;
        const float alpha = grow ? fexp2(mA - mn) : 1.0f;
        lA *= alpha;
#pragma unroll
        for (int i = 0; i < 16; ++i) { oA[0][i] *= alpha; oA[1][i] *= alpha; }
        mA = mn;
      }
      float r0 = 0.f, r1 = 0.f, r2 = 0.f, r3 = 0.f;
#pragma unroll
      for (int i = 0; i < 16; i += 4) {
        sA0[i + 0] = fexp2(sA0[i + 0] - mA); r0 += sA0[i + 0];
        sA0[i + 1] = fexp2(sA0[i + 1] - mA); r1 += sA0[i + 1];
        sA0[i + 2] = fexp2(sA0[i + 2] - mA); r2 += sA0[i + 2];
        sA0[i + 3] = fexp2(sA0[i + 3] - mA); r3 += sA0[i + 3];
        sA1[i + 0] = fexp2(sA1[i + 0] - mA); r0 += sA1[i + 0];
        sA1[i + 1] = fexp2(sA1[i + 1] - mA); r1 += sA1[i + 1];
        sA1[i + 2] = fexp2(sA1[i + 2] - mA); r2 += sA1[i + 2];
        sA1[i + 3] = fexp2(sA1[i + 3] - mA); r3 += sA1[i + 3];
      }
      lA += (r0 + r1) + (r2 + r3);
    }
    {
      float mv[8];
#pragma unroll
      for (int i = 0; i < 8; ++i)
        mv[i] = fmaxf(fmaxf(sB0[i], sB0[i + 8]), fmaxf(sB1[i], sB1[i + 8]));
#pragma unroll
      for (int i = 0; i < 4; ++i) mv[i] = fmaxf(mv[i], mv[i + 4]);
      float mx = fmaxf(fmaxf(mv[0], mv[1]), fmaxf(mv[2], mv[3]));
      mx = fmaxf(mx, __shfl_xor(mx, 32));
      const bool grow = mx > mB + 8.0f;
      if (__any(grow)) {
        const float mn = grow ? mx : mB;
        const float alpha = grow ? fexp2(mB - mn) : 1.0f;
        lB *= alpha;
#pragma unroll
        for (int i = 0; i < 16; ++i) { oB[0][i] *= alpha; oB[1][i] *= alpha; }
        mB = mn;
      }
      float r0 = 0.f, r1 = 0.f, r2 = 0.f, r3 = 0.f;
#pragma unroll
      for (int i = 0; i < 16; i += 4) {
        sB0[i + 0] = fexp2(sB0[i + 0] - mB); r0 += sB0[i + 0];
        sB0[i + 1] = fexp2(sB0[i + 1] - mB); r1 += sB0[i + 1];
        sB0[i + 2] = fexp2(sB0[i + 2] - mB); r2 += sB0[i + 2];
        sB0[i + 3] = fexp2(sB0[i + 3] - mB); r3 += sB0[i + 3];
        sB1[i + 0] = fexp2(sB1[i + 0] - mB); r0 += sB1[i + 0];
        sB1[i + 1] = fexp2(sB1[i + 1] - mB); r1 += sB1[i + 1];
        sB1[i + 2] = fexp2(sB1[i + 2] - mB); r2 += sB1[i + 2];
        sB1[i + 3] = fexp2(sB1[i + 3] - mB); r3 += sB1[i + 3];
      }
      lB += (r0 + r1) + (r2 + r3);
    }

    // ---- P -> bf16, redistribute across lane halves (in-register) ----
    // pf[2c+e] built from chunk c with kpair base bb=2e (matches R11 kg map).
    short8 pfA[4], pfB[4];
#pragma unroll
    for (int e = 0; e < 2; ++e) {
      const int bb = 2 * e;
      {
        const uint32_t u00 = pk2(sA0[4 * bb + 0], sA0[4 * bb + 1]);
        const uint32_t u01 = pk2(sA0[4 * bb + 2], sA0[4 * bb + 3]);
        const uint32_t u10 = pk2(sA0[4 * bb + 4], sA0[4 * bb + 5]);
        const uint32_t u11 = pk2(sA0[4 * bb + 6], sA0[4 * bb + 7]);
        const uint2v se0 =
            __builtin_amdgcn_permlane32_swap(u00, u10, false, false);
        const uint2v se1 =
            __builtin_amdgcn_permlane32_swap(u01, u11, false, false);
        uint32_t fr[4] = {se0.x, se1.x, se0.y, se1.y};
        pfA[e] = *reinterpret_cast<short8*>(fr);
      }
      {
        const uint32_t u00 = pk2(sA1[4 * bb + 0], sA1[4 * bb + 1]);
        const uint32_t u01 = pk2(sA1[4 * bb + 2], sA1[4 * bb + 3]);
        const uint32_t u10 = pk2(sA1[4 * bb + 4], sA1[4 * bb + 5]);
        const uint32_t u11 = pk2(sA1[4 * bb + 6], sA1[4 * bb + 7]);
        const uint2v se0 =
            __builtin_amdgcn_permlane32_swap(u00, u10, false, false);
        const uint2v se1 =
            __builtin_amdgcn_permlane32_swap(u01, u11, false, false);
        uint32_t fr[4] = {se0.x, se1.x, se0.y, se1.y};
        pfA[2 + e] = *reinterpret_cast<short8*>(fr);
      }
      {
        const uint32_t u00 = pk2(sB0[4 * bb + 0], sB0[4 * bb + 1]);
        const uint32_t u01 = pk2(sB0[4 * bb + 2], sB0[4 * bb + 3]);
        const uint32_t u10 = pk2(sB0[4 * bb + 4], sB0[4 * bb + 5]);
        const uint32_t u11 = pk2(sB0[4 * bb + 6], sB0[4 * bb + 7]);
        const uint2v se0 =
            __builtin_amdgcn_permlane32_swap(u00, u10, false, false);
        const uint2v se1 =
            __builtin_amdgcn_permlane32_swap(u01, u11, false, false);
        uint32_t fr[4] = {se0.x, se1.x, se0.y, se1.y};
        pfB[e] = *reinterpret_cast<short8*>(fr);
      }
      {
        const uint32_t u00 = pk2(sB1[4 * bb + 0], sB1[4 * bb + 1]);
        const uint32_t u01 = pk2(sB1[4 * bb + 2], sB1[4 * bb + 3]);
        const uint32_t u10 = pk2(sB1[4 * bb + 4], sB1[4 * bb + 5]);
        const uint32_t u11 = pk2(sB1[4 * bb + 6], sB1[4 * bb + 7]);
        const uint2v se0 =
            __builtin_amdgcn_permlane32_swap(u00, u10, false, false);
        const uint2v se1 =
            __builtin_amdgcn_permlane32_swap(u01, u11, false, false);
        uint32_t fr[4] = {se0.x, se1.x, se0.y, se1.y};
        pfB[2 + e] = *reinterpret_cast<short8*>(fr);
      }
    }

    // ---- O^T += V^T * P^T, both chunks (16 MFMA) ----
    __builtin_amdgcn_s_setprio(1);
#pragma unroll
    for (int dt = 0; dt < 2; ++dt)
#pragma unroll
      for (int kg = 0; kg < 4; ++kg) {
        const short8 vf = *reinterpret_cast<const short8*>(
            lds + ((8192 + (32 * dt + r31) * 128 +
                    (((32 * kg + 16 * hh)) ^ ((r31 & 7) << 4))) |
                   po));
        oA[dt] = __builtin_amdgcn_mfma_f32_32x32x16_bf16(vf, pfA[kg], oA[dt],
                                                         0, 0, 0);
        oB[dt] = __builtin_amdgcn_mfma_f32_32x32x16_bf16(vf, pfB[kg], oB[dt],
                                                         0, 0, 0);
      }
    __builtin_amdgcn_s_setprio(0);
  }

  // ---- cross-half reduce of l (lane l / l+32 hold different kpos halves) ----
  lA += __shfl_xor(lA, 32);
  lB += __shfl_xor(lB, 32);

  // ---- store partials ----
  if (lane < 32) {
    ML[(size_t)combo * S_LEN + qrowA] = float2{mA, lA};
    ML[(size_t)combo * S_LEN + qrowB] = float2{mB, lB};
  }
  ushort* obA = Opart + ((size_t)combo * S_LEN + qrowA) * HD;
  ushort* obB = Opart + ((size_t)combo * S_LEN + qrowB) * HD;
#pragma unroll
  for (int dt = 0; dt < 2; ++dt)
#pragma unroll
    for (int rq = 0; rq < 4; ++rq) {
      const int d = 32 * dt + 8 * rq + 4 * hh;
      uint2 pwA, pwB;
      pwA.x = pk2(oA[dt][4 * rq + 0], oA[dt][4 * rq + 1]);
      pwA.y = pk2(oA[dt][4 * rq + 2], oA[dt][4 * rq + 3]);
      pwB.x = pk2(oB[dt][4 * rq + 0], oB[dt][4 * rq + 1]);
      pwB.y = pk2(oB[dt][4 * rq + 2], oB[dt][4 * rq + 3]);
      *reinterpret_cast<uint2*>(obA + d) = pwA;
      *reinterpret_cast<uint2*>(obB + d) = pwB;
    }
}

// ---------------- combine the 4 kv-chunk partials (m/l merge) ----------------
__global__ __launch_bounds__(256)
void combine(const ushort* __restrict__ Opart, const float2* __restrict__ ML,
             ushort* __restrict__ ob) {
  const int t = threadIdx.x;
  const int qq = t & 63, ds = t >> 6;
  const int q = blockIdx.x * 64 + qq;
  const int h = blockIdx.y;

  float m = -1e30f, mz[NZ], lz[NZ];
#pragma unroll
  for (int z = 0; z < NZ; ++z) {
    const float2 v = ML[(size_t)(z * 8 + h) * S_LEN + q];
    mz[z] = v.x; lz[z] = v.y;
    m = fmaxf(m, v.x);
  }
  float wz[NZ], l = 0.f;
#pragma unroll
  for (int z = 0; z < NZ; ++z) {
    wz[z] = fexp2(mz[z] - m);
    l += wz[z] * lz[z];
  }
  const float inv = 1.0f / l;
#pragma unroll
  for (int z = 0; z < NZ; ++z) wz[z] *= inv;

  float acc[16];
#pragma unroll
  for (int i = 0; i < 16; ++i) acc[i] = 0.f;
#pragma unroll
  for (int z = 0; z < NZ; ++z) {
    const ushort* src =
        Opart + (((size_t)(z * 8 + h) * S_LEN) + q) * HD + ds * 16;
    const uint4 u0 = *reinterpret_cast<const uint4*>(src);
    const uint4 u1 = *reinterpret_cast<const uint4*>(src + 8);
    const ushort* e0 = reinterpret_cast<const ushort*>(&u0);
    const ushort* e1 = reinterpret_cast<const ushort*>(&u1);
#pragma unroll
    for (int i = 0; i < 8; ++i) {
      acc[i] = fmaf(wz[z], bf2f(e0[i]), acc[i]);
      acc[i + 8] = fmaf(wz[z], bf2f(e1[i]), acc[i + 8]);
    }
  }
  uint32_t pk[8];
#pragma unroll
  for (int i = 0; i < 8; ++i)
    pk[i] = pk2(acc[2 * i], acc[2 * i + 1]);
  ushort* dst = ob + (size_t)q * DIM + h * 64 + ds * 16;
  *reinterpret_cast<uint4*>(dst) = *reinterpret_cast<uint4*>(pk);
  *reinterpret_cast<uint4*>(dst + 8) = *reinterpret_cast<uint4*>(pk + 4);
}

extern "C" void kernel_launch(void* const* d_in, const int* in_sizes, int n_in,
                              void* d_out, int out_size, void* d_ws, size_t ws_size,
                              hipStream_t stream) {
  const float* x  = (const float*)d_in[0];
  const float* qp = (const float*)d_in[1];
  const float* kp = (const float*)d_in[2];
  const float* vp = (const float*)d_in[3];
  const float* pp = (const float*)d_in[4];
  float* out = (float*)d_out;

  unsigned char* ws = (unsigned char*)d_ws;
  ushort* xb    = (ushort*)(ws);                       // 4 MB
  ushort* qkvb  = (ushort*)(ws + ((size_t)4 << 20));   // 12 MB [3][8] planes
  ushort* ob    = (ushort*)(ws + ((size_t)16 << 20));  // 4 MB [4096][512]
  ushort* wbT   = (ushort*)(ws + ((size_t)20 << 20));  // 1.5 MB
  ushort* ppT   = (ushort*)(ws + ((size_t)22 << 20));  // 0.5 MB
  ushort* opart = (ushort*)(ws + ((size_t)23 << 20));  // 16 MB [32][4096][64]
  float2* ml    = (float2*)(ws + ((size_t)39 << 20));  // 1 MB [32][4096]

  cast_x<<<dim3(1024), dim3(256), 0, stream>>>(x, xb);
  transpose_w<<<dim3(8, 8, 4), dim3(256), 0, stream>>>(qp, kp, vp, pp, wbT, ppT);
  gemm_bf16<0><<<dim3(32, 24), dim3(256), 0, stream>>>(xb, wbT, qkvb);
  attn_mfma32<<<dim3(32, 16), dim3(256), 0, stream>>>(qkvb, opart, ml);
  combine<<<dim3(64, 8), dim3(256), 0, stream>>>(opart, ml, ob);
  gemm_bf16<1><<<dim3(32, 8), dim3(256), 0, stream>>>(ob, ppT, out);
}